// Round 11
// baseline (81.654 us; speedup 1.0000x reference)
//
#include <hip/hip_runtime.h>
#include <stdint.h>

typedef unsigned long long u64;
typedef unsigned int u32;

#define BN 2
#define DD 32
#define HH 192
#define WW 192
#define NV (DD*HH*WW)   /* 1179648 */
#define KK 8
#define NSL_S 576       /* k_stats blocks per batch (2048 vox each) */
#define VPB_S 2048
#define NSL_H 288       /* k_hist blocks per batch (4096 vox each) */
#define VPB_H 4096
#define NB 256          /* buckets in window */
#define BOFF 1808       /* 0x38800000>>19 : window floor e = 2^-14 */
#define L2E 1.44269504f
#define SSLOT 11        /* ssh slots per cell */

__device__ __forceinline__ u64 fx(float v){ return (u64)(long long)llrintf(v*4294967296.0f); }
__device__ __forceinline__ float unfx(u64 v){ return (float)((double)(long long)v*(1.0/4294967296.0)); }
__device__ __forceinline__ u32 fx12(float v){ return (u32)(int)llrintf(v*4096.0f); }
__device__ __forceinline__ float unfx12(u64 v){ return (float)((double)(long long)v*(1.0/4096.0)); }
__device__ __forceinline__ float rcp_f(float x){ return __builtin_amdgcn_rcpf(x); }
__device__ __forceinline__ float exp2_f(float x){ return __builtin_amdgcn_exp2f(x); }
__device__ __forceinline__ float tanh_f(float x){ return 1.f - 2.f*rcp_f(1.f + exp2_f(x*(2.f*L2E))); }
__device__ __forceinline__ float sigm_f(float x){ return rcp_f(1.f + exp2_f(-x*L2E)); }
__device__ __forceinline__ float rfl(float x){ return __uint_as_float(__builtin_amdgcn_readfirstlane((int)__float_as_uint(x))); }

// derive raw sums for cell (b,k) from 4 shards
struct Cell { float cnt, cmc, mx, my, mz, g0, g1, g2, h, cmx, cmy, cmz; };
__device__ __forceinline__ Cell load_cell(const u64* __restrict__ ssh, int bb, int kq){
    u64 st[SSLOT];
    #pragma unroll
    for (int s = 0; s < SSLOT; s++){
        u64 a = 0ull;
        #pragma unroll
        for (int sh = 0; sh < 4; sh++)
            a += ssh[((size_t)(sh*BN + bb)*KK + kq)*SSLOT + s];
        st[s] = a;
    }
    Cell c;
    c.cnt = (float)(long long)(st[0] >> 32);
    c.cmc = (float)(u32)st[0];
    c.mx = (float)(long long)st[1] * (1.f/(WW-1));
    c.my = (float)(long long)st[2] * (1.f/(HH-1));
    c.mz = (float)(long long)st[3] * (1.f/(DD-1));
    c.g0 = unfx12(st[4]); c.g1 = unfx12(st[5]); c.g2 = unfx12(st[6]);
    c.h  = unfx12(st[7]);
    c.cmx = unfx(st[8]); c.cmy = unfx(st[9]); c.cmz = unfx(st[10]);
    return c;
}

// ---------------- detection of center_images storage layout ----------------
__global__ void k_detect(const u32* __restrict__ w, int nwords, u32* flags){
    u32 fF=0,fB=0,fO=0,f1=0;
    for (int i = blockIdx.x*blockDim.x + threadIdx.x; i < nwords; i += gridDim.x*blockDim.x){
        u32 x = w[i];
        if (x == 0x3F800000u) fF = 1;
        else if (x > 1u) fB = 1;
        else if (x == 1u){ f1 = 1; if (i & 1) fO = 1; }
    }
    if (fF) atomicOr(&flags[0], 1u);
    if (fB) atomicOr(&flags[1], 1u);
    if (fO) atomicOr(&flags[2], 1u);
    if (f1) atomicOr(&flags[3], 1u);
}

// ---------------- per-instance statistics, all-u32 LDS atomics ----------------
// bins32 slots: 0 packA=(cnt<<20|iz<<4|cm), 1 sum_ix, 2 sum_iy, 3..5 s0..s2 (fx12), 6 s2tot (fx12)
// ssh[shard4][b][k][11] u64: 0 cnt<<32|cm, 1..3 sum_ix/iy/iz, 4..7 sig fx12, 8..10 cm_xyz fx32
__global__ __launch_bounds__(512, 8) void k_stats(
        const float* __restrict__ pred,
        const int* __restrict__ inst, const int* __restrict__ lab,
        const void* __restrict__ cim, const u32* __restrict__ flags,
        u64* __restrict__ ssh, u64* __restrict__ bgsh){
    int sx = blockIdx.x, b = blockIdx.y;
    __shared__ u32 bins32[8][4][KK][7];  /* 32 replicas, stride 7: 7 KB */
    __shared__ u64 cmb[8][KK][4];        /* rare cm sums, per-wave: 2 KB */
    __shared__ u64 bgsum;
    for (int i = threadIdx.x; i < 8*4*KK*7; i += 512) ((u32*)bins32)[i] = 0u;
    for (int i = threadIdx.x; i < 8*KK*4; i += 512) ((u64*)cmb)[i] = 0ull;
    if (threadIdx.x == 0) bgsum = 0ull;
    __syncthreads();
    int mode = flags[0] ? 2 : (flags[1] ? 1 : (flags[2] ? 0 : (flags[3] ? 3 : 0)));
    const float* pb = pred + (size_t)b*7*NV;
    const int* ib = inst + (size_t)b*NV;
    const int* lb = lab + (size_t)b*NV;
    int wv = threadIdx.x >> 6, lp = threadIdx.x & 3;
    int g = sx*VPB_S + threadIdx.x*4;

    float4 s0v = *(const float4*)&pb[3*(size_t)NV + g];
    float4 s1v = *(const float4*)&pb[4*(size_t)NV + g];
    float4 s2v = *(const float4*)&pb[5*(size_t)NV + g];
    float4 s6v = *(const float4*)&pb[6*(size_t)NV + g];
    int4 iv4 = *(const int4*)&ib[g];
    int4 lb4 = *(const int4*)&lb[g];
    int iy = g / WW;
    int ix = g - iy*WW;
    int iz = iy / HH; iy -= iz*HH;
    u64 fxm = fx(ix*(1.f/(WW-1)));
    u64 fdx = fx(1.f/(WW-1));
    u64 fym = fx(iy*(1.f/(HH-1)));
    u64 fzm = fx(iz*(1.f/(DD-1)));
    u32 cv4 = 0;
    size_t gi = (size_t)b*NV + g;
    if (mode == 0){
        int4 c = *(const int4*)&((const int*)cim)[gi];
        cv4 = (c.x?1u:0u)|(c.y?2u:0u)|(c.z?4u:0u)|(c.w?8u:0u);
    } else if (mode == 1){
        u32 c = *(const u32*)&((const unsigned char*)cim)[gi];
        cv4 = ((c&0xFFu)?1u:0u)|((c&0xFF00u)?2u:0u)|((c&0xFF0000u)?4u:0u)|((c&0xFF000000u)?8u:0u);
    } else if (mode == 2){
        float4 c = *(const float4*)&((const float*)cim)[gi];
        cv4 = (c.x!=0.f?1u:0u)|(c.y!=0.f?2u:0u)|(c.z!=0.f?4u:0u)|(c.w!=0.f?8u:0u);
    } else {
        int4 c0 = *(const int4*)&((const int*)cim)[2*gi];
        int4 c1 = *(const int4*)&((const int*)cim)[2*gi + 4];
        cv4 = (c0.x?1u:0u)|(c0.z?2u:0u)|(c1.x?4u:0u)|(c1.z?8u:0u);
    }
    float s0a[4] = {s0v.x,s0v.y,s0v.z,s0v.w};
    float s1a[4] = {s1v.x,s1v.y,s1v.z,s1v.w};
    float s2a[4] = {s2v.x,s2v.y,s2v.z,s2v.w};
    float s6a[4] = {s6v.x,s6v.y,s6v.z,s6v.w};
    int iva[4] = {iv4.x,iv4.y,iv4.z,iv4.w};
    int lba[4] = {lb4.x,lb4.y,lb4.z,lb4.w};
    float bgacc = 0.f;
    #pragma unroll
    for (int j = 0; j < 4; j++){
        float seed = sigm_f(s6a[j]);
        if (lba[j] == 0) bgacc += seed*seed;
        int iv = iva[j];
        if (iv >= 1 && iv <= KK){
            u32* bn = &bins32[wv][lp][iv-1][0];
            u32 cv = (cv4 >> j) & 1u;
            atomicAdd(&bn[0], (1u << 20) | ((u32)iz << 4) | cv);
            atomicAdd(&bn[1], (u32)(ix + j));
            atomicAdd(&bn[2], (u32)iy);
            atomicAdd(&bn[3], fx12(s0a[j]));
            atomicAdd(&bn[4], fx12(s1a[j]));
            atomicAdd(&bn[5], fx12(s2a[j]));
            atomicAdd(&bn[6], fx12(s0a[j]*s0a[j] + s1a[j]*s1a[j] + s2a[j]*s2a[j]));
            if (cv){
                u64* cb = &cmb[wv][iv-1][0];
                atomicAdd(&cb[0], fxm + (u64)j*fdx);
                atomicAdd(&cb[1], fym);
                atomicAdd(&cb[2], fzm);
            }
        }
    }
    #pragma unroll
    for (int off = 32; off > 0; off >>= 1) bgacc += __shfl_down(bgacc, off);
    if ((threadIdx.x & 63) == 0 && bgacc != 0.f) atomicAdd(&bgsum, fx(bgacc));
    __syncthreads();
    if (threadIdx.x == 0 && bgsum) atomicAdd(&bgsh[(size_t)b*8 + (sx&7)], bgsum);
    /* merge: one thread per (k, slot) */
    int t = threadIdx.x;
    u64* cell0 = &ssh[((size_t)((sx&3)*BN + b))*KK*SSLOT];
    if (t < KK*7){
        int k = t / 7, s = t - k*7;
        u32 acc = 0u;
        #pragma unroll
        for (int r = 0; r < 32; r++) acc += bins32[r>>2][r&3][k][s];
        u64* cell = cell0 + (size_t)k*SSLOT;
        if (s == 0){
            if (acc){
                u64 cnt = acc >> 20, siz = (acc >> 4) & 0xFFFFu, cm = acc & 15u;
                atomicAdd(&cell[0], (cnt << 32) | cm);
                if (siz) atomicAdd(&cell[3], siz);
            }
        } else if (s < 3){
            if (acc) atomicAdd(&cell[s], (u64)acc);
        } else {
            if (acc) atomicAdd(&cell[s + 1], (u64)(long long)(int)acc);  /* 4..7, sign-extended */
        }
    }
    if (t < KK*3){
        int k = t / 3, s = t - k*3;
        u64 acc = 0ull;
        #pragma unroll
        for (int w = 0; w < 8; w++) acc += cmb[w][k][s];
        if (acc) atomicAdd(&cell0[(size_t)k*SSLOT + 8 + s], acc);
    }
}

// ---------------- single-pass all-k windowed histogram, 8 vox/thread ----------------
__global__ __launch_bounds__(512, 4) void k_hist(
        const u64* __restrict__ ssh, const float* __restrict__ pred,
        const int* __restrict__ inst, u32* __restrict__ hs, u64* __restrict__ bgsh){
    __shared__ u32 lh[KK*2*NB];   /* 16 KB */
    __shared__ u64 fgfx;
    __shared__ float dv[KK*6];
    int sx = blockIdx.x, b = blockIdx.y;
    if (threadIdx.x == 0) fgfx = 0ull;
    for (int i = threadIdx.x; i < KK*2*NB; i += 512) lh[i] = 0u;
    if (threadIdx.x < KK){   /* per-block derive of this b's 8 instance consts */
        int kq = threadIdx.x;
        Cell c = load_cell(ssh, b, kq);
        float safe = fmaxf(c.cnt, 1.f);
        float isafe = 1.f/safe;
        float c0 = (c.cmc == 1.f) ? c.cmx : c.mx*isafe;
        float c1 = (c.cmc == 1.f) ? c.cmy : c.my*isafe;
        float c2 = (c.cmc == 1.f) ? c.cmz : c.mz*isafe;
        dv[kq*6+0] = expf(10.f*c.g0*isafe)*L2E;
        dv[kq*6+1] = expf(10.f*c.g1*isafe)*L2E;
        dv[kq*6+2] = expf(10.f*c.g2*isafe)*L2E;
        dv[kq*6+3] = c0; dv[kq*6+4] = c1; dv[kq*6+5] = c2;
    }
    __syncthreads();
    float ax[KK], ay[KK], az[KK], cx[KK], cy[KK], cz[KK];
    #pragma unroll
    for (int k = 0; k < KK; k++){
        ax[k]=rfl(dv[k*6+0]); ay[k]=rfl(dv[k*6+1]); az[k]=rfl(dv[k*6+2]);
        cx[k]=rfl(dv[k*6+3]); cy[k]=rfl(dv[k*6+4]); cz[k]=rfl(dv[k*6+5]);
    }
    const float* pb = pred + (size_t)b*7*NV;
    const int* ib = inst + (size_t)b*NV;
    int g = sx*VPB_H + threadIdx.x*8;
    const float4* q0 = (const float4*)&pb[g];
    const float4* q1 = (const float4*)&pb[(size_t)NV + g];
    const float4* q2 = (const float4*)&pb[2*(size_t)NV + g];
    const float4* q6 = (const float4*)&pb[6*(size_t)NV + g];
    float4 a0 = q0[0], b0 = q0[1];
    float4 a1 = q1[0], b1 = q1[1];
    float4 a2 = q2[0], b2 = q2[1];
    float4 a6 = q6[0], b6 = q6[1];
    const int4* qi = (const int4*)&ib[g];
    int4 i0 = qi[0], i1 = qi[1];
    int iy = g / WW;
    int ix = g - iy*WW;
    int iz = iy / HH; iy -= iz*HH;
    float xm = ix*(1.f/(WW-1)), ym = iy*(1.f/(HH-1)), zm = iz*(1.f/(DD-1));
    float p0a[8] = {a0.x,a0.y,a0.z,a0.w,b0.x,b0.y,b0.z,b0.w};
    float p1a[8] = {a1.x,a1.y,a1.z,a1.w,b1.x,b1.y,b1.z,b1.w};
    float p2a[8] = {a2.x,a2.y,a2.z,a2.w,b2.x,b2.y,b2.z,b2.w};
    float p6a[8] = {a6.x,a6.y,a6.z,a6.w,b6.x,b6.y,b6.z,b6.w};
    int iva[8] = {i0.x,i0.y,i0.z,i0.w,i1.x,i1.y,i1.z,i1.w};
    float e0[8], e1[8], e2[8], sd[8];
    #pragma unroll
    for (int j = 0; j < 8; j++){
        e0[j] = tanh_f(p0a[j]) + xm + j*(1.f/(WW-1));
        e1[j] = tanh_f(p1a[j]) + ym;
        e2[j] = tanh_f(p2a[j]) + zm;
        sd[j] = sigm_f(p6a[j]);
    }
    float fgacc = 0.f;
    #pragma unroll
    for (int k = 0; k < KK; k++){
        #pragma unroll
        for (int j = 0; j < 8; j++){
            float d0 = e0[j] - cx[k], d1 = e1[j] - cy[k], dz = e2[j] - cz[k];
            float d2 = ax[k]*d0*d0;
            d2 = fmaf(ay[k]*d1, d1, d2);
            d2 = fmaf(az[k]*dz, dz, d2);
            float dist = exp2_f(-d2);               /* L2E folded into a's */
            if (iva[j] == k + 1){
                float e = fmaf(-2.f, dist, 2.f);
                int bu = (int)(__float_as_uint(e) >> 19) - BOFF;
                bu = bu < 0 ? 0 : (bu > NB-1 ? NB-1 : bu);
                atomicAdd(&lh[k*512 + bu], 1u);
                fgacc += (sd[j] - dist)*(sd[j] - dist);
            } else {
                /* e = 2*dist: bits(2x)>>19 == (bits(x)>>19)+16 for normals */
                int bu = (int)(__float_as_uint(dist) >> 19) - (BOFF - 16);
                bu = bu < 0 ? 0 : (bu > NB-1 ? NB-1 : bu);
                atomicAdd(&lh[k*512 + NB + bu], 1u);
            }
        }
    }
    #pragma unroll
    for (int off = 32; off > 0; off >>= 1) fgacc += __shfl_down(fgacc, off);
    if ((threadIdx.x & 63) == 0 && fgacc != 0.f) atomicAdd(&fgfx, fx(fgacc));
    __syncthreads();
    if (threadIdx.x == 0 && fgfx) atomicAdd(&bgsh[(size_t)(2+b)*8 + (sx&7)], fgfx);
    u32* out = hs + ((size_t)b*NSL_H + sx)*(KK*NB);
    for (int i = threadIdx.x; i < KK*NB; i += 512){
        int k = i >> 8, bu = i & 255;
        out[i] = (lh[k*512 + bu] << 16) | lh[k*512 + NB + bu];
    }
}

// ---------------- Lovasz scan + prologue-derive + fused final (16 blocks) ----------------
__global__ __launch_bounds__(1024) void k_lovasz(
        const u32* __restrict__ hs, const u64* __restrict__ ssh,
        float* __restrict__ lov, const u64* __restrict__ bgsh,
        u32* __restrict__ counter, float* __restrict__ out){
    int bk = blockIdx.x, b = bk >> 3, k = bk & 7;
    int t = threadIdx.x;
    __shared__ float s_cnt[16], s_vrk[16], s_val[16];
    if (t < 16){
        Cell c = load_cell(ssh, t >> 3, t & 7);
        float safe = fmaxf(c.cnt, 1.f);
        float isafe = 1.f/safe;
        float sm0 = c.g0*isafe, sm1 = c.g1*isafe, sm2 = c.g2*isafe;
        float vs = c.h - 2.f*(sm0*c.g0 + sm1*c.g1 + sm2*c.g2)
                 + (sm0*sm0 + sm1*sm1 + sm2*sm2)*c.cnt;
        s_vrk[t] = vs*isafe*(1.f/3.f);
        s_val[t] = c.cnt > 0.f ? 1.f : 0.f;
        s_cnt[t] = c.cnt;
    }
    __syncthreads();
    float gts = s_cnt[bk];
    float obj = fmaxf(s_val[b*8+0]+s_val[b*8+1]+s_val[b*8+2]+s_val[b*8+3]
                     +s_val[b*8+4]+s_val[b*8+5]+s_val[b*8+6]+s_val[b*8+7], 1.f);
    float coef = s_val[bk]/obj;
    float lv = 0.f;
    __shared__ u64 part[4][NB];
    __shared__ u64 wsum[4];
    __shared__ float racc[NB];
    if (gts >= 0.5f){
        int bu = (NB - 1) - (t & 255);    /* descending error order */
        int sg = t >> 8;
        u32 np = 0, nn = 0;
        const u32* base = hs + (size_t)b*NSL_H*(KK*NB) + k*NB + bu;
        for (int s = sg; s < NSL_H; s += 4){
            u32 h = base[(size_t)s*(KK*NB)];
            np += h >> 16; nn += h & 0xFFFFu;
        }
        part[sg][t & 255] = ((u64)np << 32) | nn;
        __syncthreads();
        u64 pack = 0ull, inc = 0ull;
        if (t < NB){
            pack = part[0][t] + part[1][t] + part[2][t] + part[3][t];
            int lane = t & 63;
            inc = pack;
            #pragma unroll
            for (int off = 1; off < 64; off <<= 1){
                u64 n = __shfl_up(inc, off);
                if (lane >= off) inc += n;
            }
            if (lane == 63) wsum[t >> 6] = inc;
        }
        __syncthreads();
        if (t < 4){
            u64 x = wsum[t];
            #pragma unroll
            for (int off = 1; off < 4; off <<= 1){
                u64 n = __shfl_up(x, off);
                if (t >= off) x += n;
            }
            wsum[t] = x;
        }
        __syncthreads();
        float acc = 0.f;
        if (t < NB){
            int wid = t >> 6;
            u64 excl = inc - pack + (wid ? wsum[wid - 1] : 0ull);
            u32 np2 = (u32)(pack >> 32), nn2 = (u32)pack;
            if (np2 | nn2){
                int bu2 = (NB - 1) - t;
                float Pe = (float)(u32)(excl >> 32), Qe = (float)(u32)excl;
                float Pi = Pe + (float)np2, Qi = Qe + (float)nn2;
                float je = 1.f - (gts - Pe)/(gts + Qe);
                float ji = 1.f - (gts - Pi)/(gts + Qi);
                u32 bits = ((u32)(bu2 + BOFF) << 19) | (1u << 18);
                if (bits > 0x40000000u) bits = 0x40000000u;
                acc = __uint_as_float(bits) * (ji - je);
            }
            racc[t] = acc;
        }
        __syncthreads();
        for (int off = 128; off > 0; off >>= 1){
            if (t < off) racc[t] += racc[t + off];
            __syncthreads();
        }
        lv = coef * racc[0];
    }
    if (t == 0){
        __hip_atomic_store(&lov[bk], lv, __ATOMIC_RELEASE, __HIP_MEMORY_SCOPE_AGENT);
        u32 ticket = __hip_atomic_fetch_add(counter, 1u, __ATOMIC_ACQ_REL, __HIP_MEMORY_SCOPE_AGENT);
        if (ticket == 15u){
            float tot = 0.f;
            for (int i = 0; i < 16; i++)
                tot += __hip_atomic_load(&lov[i], __ATOMIC_ACQUIRE, __HIP_MEMORY_SCOPE_AGENT);
            for (int b2 = 0; b2 < BN; b2++){
                float objb = fmaxf(s_val[b2*8+0]+s_val[b2*8+1]+s_val[b2*8+2]+s_val[b2*8+3]
                                  +s_val[b2*8+4]+s_val[b2*8+5]+s_val[b2*8+6]+s_val[b2*8+7], 1.f);
                float vp = 0.f;
                for (int kq = 0; kq < 8; kq++) vp += s_val[b2*8+kq]*s_vrk[b2*8+kq];
                float bg = 0.f, fg = 0.f;
                for (int sh = 0; sh < 8; sh++){
                    bg += unfx(bgsh[(size_t)b2*8 + sh]);
                    fg += unfx(bgsh[(size_t)(2+b2)*8 + sh]);
                }
                tot += 10.f*vp/objb + (bg + fg)*(1.f/(float)NV);
            }
            out[0] = tot * 0.5f;
        }
    }
}

extern "C" void kernel_launch(void* const* d_in, const int* in_sizes, int n_in,
                              void* d_out, int out_size, void* d_ws, size_t ws_size,
                              hipStream_t stream){
    const float* pred = (const float*)d_in[0];
    const int*   inst = (const int*)d_in[2];
    const int*   lab  = (const int*)d_in[3];
    const void*  cim  = d_in[4];

    char* ws = (char*)d_ws;
    size_t off = 0;
    u32* hs = (u32*)(ws + off);        off += (size_t)BN*NSL_H*KK*NB*4;  /* 4.72 MB */
    size_t small0 = off;
    u64* ssh = (u64*)(ws + off);       off += (size_t)4*BN*KK*SSLOT*8;   /* stat shards */
    u64* bgsh = (u64*)(ws + off);      off += (size_t)4*8*8;             /* bg/fg shards */
    float* lov = (float*)(ws + off);   off += 16*4;
    u32* flags = (u32*)(ws + off);     off += 4*4;
    u32* counter = (u32*)(ws + off);   off += 4;

    (void)hipMemsetAsync(ws + small0, 0, off - small0, stream);
    k_detect<<<dim3(256), dim3(256), 0, stream>>>((const u32*)cim, BN*NV/4, flags);
    k_stats<<<dim3(NSL_S, BN), dim3(512), 0, stream>>>(pred, inst, lab, cim, flags, ssh, bgsh);
    k_hist<<<dim3(NSL_H, BN), dim3(512), 0, stream>>>(ssh, pred, inst, hs, bgsh);
    k_lovasz<<<16, 1024, 0, stream>>>(hs, ssh, lov, bgsh, counter, (float*)d_out);
}

// Round 12
// 78.055 us; speedup vs baseline: 1.0461x; 1.0461x over previous
//
#include <hip/hip_runtime.h>
#include <stdint.h>

typedef unsigned long long u64;
typedef unsigned int u32;

#define BN 2
#define DD 32
#define HH 192
#define WW 192
#define NV (DD*HH*WW)   /* 1179648 */
#define KK 8
#define NSL 288         /* blocks per batch, 4096 vox each, within one z-slice */
#define VPB 4096
#define NB 256          /* buckets in window */
#define BOFF 1808       /* 0x38800000>>19 : window floor e = 2^-14 */
#define L2E 1.44269504f
#define SSLOT 11

__device__ __forceinline__ u64 fx(float v){ return (u64)(long long)llrintf(v*4294967296.0f); }
__device__ __forceinline__ float unfx(u64 v){ return (float)((double)(long long)v*(1.0/4294967296.0)); }
__device__ __forceinline__ float rcp_f(float x){ return __builtin_amdgcn_rcpf(x); }
__device__ __forceinline__ float exp2_f(float x){ return __builtin_amdgcn_exp2f(x); }
__device__ __forceinline__ float tanh_f(float x){ return 1.f - 2.f*rcp_f(1.f + exp2_f(x*(2.f*L2E))); }
__device__ __forceinline__ float sigm_f(float x){ return rcp_f(1.f + exp2_f(-x*L2E)); }
__device__ __forceinline__ float rfl(float x){ return __uint_as_float(__builtin_amdgcn_readfirstlane((int)__float_as_uint(x))); }

// ---------------- detection of center_images storage layout ----------------
__global__ void k_detect(const u32* __restrict__ w, int nwords, u32* flags){
    u32 fF=0,fB=0,fO=0,f1=0;
    for (int i = blockIdx.x*blockDim.x + threadIdx.x; i < nwords; i += gridDim.x*blockDim.x){
        u32 x = w[i];
        if (x == 0x3F800000u) fF = 1;
        else if (x > 1u) fB = 1;
        else if (x == 1u){ f1 = 1; if (i & 1) fO = 1; }
    }
    if (fF) atomicOr(&flags[0], 1u);
    if (fB) atomicOr(&flags[1], 1u);
    if (fO) atomicOr(&flags[2], 1u);
    if (f1) atomicOr(&flags[3], 1u);
}

// ---------------- per-instance statistics: 3 packed u64 LDS atomics/voxel ----------------
// replica slot layout (stride 25 u64): [k*3+0]=cnt<<44|Six<<24|Siy<<4|cm
//   [k*3+1]=S(s0+16)*4096<<32 | S(s1+16)*4096   [k*3+2]=S(s2+16)*4096<<32 | S(s2tot)*2048
// ssh[shard4][b][k][11]: 0 cnt<<32|cm, 1..3 Six/Siy/Siz, 4..6 Ss*4096 (signed), 7 Ss2*2048, 8..10 cm fx32
__global__ __launch_bounds__(512, 8) void k_stats(
        const float* __restrict__ pred,
        const int* __restrict__ inst,
        const void* __restrict__ cim, const u32* __restrict__ flags,
        u64* __restrict__ ssh, u64* __restrict__ bgsh){
    int sx = blockIdx.x, b = blockIdx.y;
    __shared__ u64 bins[8][4][25];       /* 32 replicas, stride 25: 6.4 KB */
    __shared__ u64 cmb[8][KK][4];        /* rare cm sums, per-wave: 2 KB */
    for (int i = threadIdx.x; i < 8*4*25; i += 512) ((u64*)bins)[i] = 0ull;
    for (int i = threadIdx.x; i < 8*KK*4; i += 512) ((u64*)cmb)[i] = 0ull;
    __syncthreads();
    int mode = flags[0] ? 2 : (flags[1] ? 1 : (flags[2] ? 0 : (flags[3] ? 3 : 0)));
    const float* pb = pred + (size_t)b*7*NV;
    const int* ib = inst + (size_t)b*NV;
    int wv = threadIdx.x >> 6, lp = threadIdx.x & 3;
    int g = sx*VPB + threadIdx.x*8;

    const float4* q0p = (const float4*)&pb[3*(size_t)NV + g];
    const float4* q1p = (const float4*)&pb[4*(size_t)NV + g];
    const float4* q2p = (const float4*)&pb[5*(size_t)NV + g];
    float4 sa0 = q0p[0], sb0 = q0p[1];
    float4 sa1 = q1p[0], sb1 = q1p[1];
    float4 sa2 = q2p[0], sb2 = q2p[1];
    const int4* qi = (const int4*)&ib[g];
    int4 i0 = qi[0], i1 = qi[1];
    int iy = g / WW;
    int ix = g - iy*WW;
    int iz = iy / HH; iy -= iz*HH;
    u64 fxm = fx(ix*(1.f/(WW-1)));
    u64 fdx = fx(1.f/(WW-1));
    u64 fym = fx(iy*(1.f/(HH-1)));
    u64 fzm = fx(iz*(1.f/(DD-1)));
    u32 cv8 = 0;
    size_t gi = (size_t)b*NV + g;
    if (mode == 0){
        int4 c0 = ((const int4*)&((const int*)cim)[gi])[0];
        int4 c1 = ((const int4*)&((const int*)cim)[gi])[1];
        cv8 = (c0.x?1u:0u)|(c0.y?2u:0u)|(c0.z?4u:0u)|(c0.w?8u:0u)
            | (c1.x?16u:0u)|(c1.y?32u:0u)|(c1.z?64u:0u)|(c1.w?128u:0u);
    } else if (mode == 1){
        u64 c = *(const u64*)&((const unsigned char*)cim)[gi];
        #pragma unroll
        for (int j = 0; j < 8; j++) if ((c >> (8*j)) & 0xFFull) cv8 |= 1u << j;
    } else if (mode == 2){
        float4 c0 = ((const float4*)&((const float*)cim)[gi])[0];
        float4 c1 = ((const float4*)&((const float*)cim)[gi])[1];
        cv8 = (c0.x!=0.f?1u:0u)|(c0.y!=0.f?2u:0u)|(c0.z!=0.f?4u:0u)|(c0.w!=0.f?8u:0u)
            | (c1.x!=0.f?16u:0u)|(c1.y!=0.f?32u:0u)|(c1.z!=0.f?64u:0u)|(c1.w!=0.f?128u:0u);
    } else {
        const int4* cc = (const int4*)&((const int*)cim)[2*gi];
        int4 c0 = cc[0], c1 = cc[1], c2 = cc[2], c3 = cc[3];
        cv8 = (c0.x?1u:0u)|(c0.z?2u:0u)|(c1.x?4u:0u)|(c1.z?8u:0u)
            | (c2.x?16u:0u)|(c2.z?32u:0u)|(c3.x?64u:0u)|(c3.z?128u:0u);
    }
    float s0a[8] = {sa0.x,sa0.y,sa0.z,sa0.w,sb0.x,sb0.y,sb0.z,sb0.w};
    float s1a[8] = {sa1.x,sa1.y,sa1.z,sa1.w,sb1.x,sb1.y,sb1.z,sb1.w};
    float s2a[8] = {sa2.x,sa2.y,sa2.z,sa2.w,sb2.x,sb2.y,sb2.z,sb2.w};
    int iva[8] = {i0.x,i0.y,i0.z,i0.w,i1.x,i1.y,i1.z,i1.w};
    #pragma unroll
    for (int j = 0; j < 8; j++){
        int iv = iva[j];
        if (iv >= 1 && iv <= KK){
            u64* bn = &bins[wv][lp][(iv-1)*3];
            u32 cv = (cv8 >> j) & 1u;
            u32 q0 = (u32)llrintf((s0a[j] + 16.f)*4096.f);
            u32 q1 = (u32)llrintf((s1a[j] + 16.f)*4096.f);
            u32 q2 = (u32)llrintf((s2a[j] + 16.f)*4096.f);
            float s2t = s0a[j]*s0a[j] + s1a[j]*s1a[j] + s2a[j]*s2a[j];
            u32 r = (u32)llrintf(fminf(s2t, 512.f)*2048.f);
            atomicAdd(&bn[0], (1ull << 44) | ((u64)(u32)(ix + j) << 24) | ((u64)(u32)iy << 4) | cv);
            atomicAdd(&bn[1], ((u64)q0 << 32) | q1);
            atomicAdd(&bn[2], ((u64)q2 << 32) | r);
            if (cv){
                u64* cb = &cmb[wv][iv-1][0];
                atomicAdd(&cb[0], fxm + (u64)j*fdx);
                atomicAdd(&cb[1], fym);
                atomicAdd(&cb[2], fzm);
            }
        }
    }
    __syncthreads();
    int t = threadIdx.x;
    u64* cell0 = &ssh[((size_t)((sx&3)*BN + b))*KK*SSLOT];
    if (t < KK){
        int k = t;
        u64 sA = 0ull, sB = 0ull, sC = 0ull;
        #pragma unroll
        for (int r2 = 0; r2 < 32; r2++){
            const u64* bn = &bins[r2>>2][r2&3][k*3];
            sA += bn[0]; sB += bn[1]; sC += bn[2];
        }
        u64 cnt = sA >> 44;
        if (cnt){
            u64 six = (sA >> 24) & 0xFFFFFull;
            u64 siy = (sA >> 4) & 0xFFFFFull;
            u64 cm  = sA & 0xFull;
            long long bias = (long long)(cnt * 65536ull);   /* 16*4096 */
            long long g0 = (long long)(sB >> 32) - bias;
            long long g1 = (long long)(sB & 0xFFFFFFFFull) - bias;
            long long g2 = (long long)(sC >> 32) - bias;
            u64 h = sC & 0xFFFFFFFFull;
            u64* cell = cell0 + (size_t)k*SSLOT;
            atomicAdd(&cell[0], (cnt << 32) | cm);
            atomicAdd(&cell[1], six);
            atomicAdd(&cell[2], siy);
            atomicAdd(&cell[3], cnt*(u64)iz);
            atomicAdd(&cell[4], (u64)g0);
            atomicAdd(&cell[5], (u64)g1);
            atomicAdd(&cell[6], (u64)g2);
            atomicAdd(&cell[7], h);
        }
    }
    if (t < KK*3){
        int k = t / 3, s = t - k*3;
        u64 acc = 0ull;
        #pragma unroll
        for (int w = 0; w < 8; w++) acc += cmb[w][k][s];
        if (acc) atomicAdd(&cell0[(size_t)k*SSLOT + 8 + s], acc);
    }
}

// ---------------- derive per-instance constants ----------------
// derived[(b*KK+k)*8]: 0..2 s_exp*L2E, 3..5 center, 6 gts(count), 7 coef(valid/obj)
__global__ void k_derive(const u64* __restrict__ ssh, float* __restrict__ derived,
                         float* __restrict__ var_part){
    int t = threadIdx.x;
    __shared__ float s_val[16], s_vrk[16], s_obj[2];
    if (t < 16){
        int bb = t >> 3, kq = t & 7;
        u64 st[SSLOT];
        #pragma unroll
        for (int s = 0; s < SSLOT; s++){
            u64 a = 0ull;
            #pragma unroll
            for (int sh = 0; sh < 4; sh++)
                a += ssh[((size_t)(sh*BN + bb)*KK + kq)*SSLOT + s];
            st[s] = a;
        }
        float cnt = (float)(long long)(st[0] >> 32);
        float cmc = (float)(u32)st[0];
        float mx = (float)(long long)st[1] * (1.f/(WW-1));
        float my = (float)(long long)st[2] * (1.f/(HH-1));
        float mz = (float)(long long)st[3] * (1.f/(DD-1));
        float g0 = (float)((double)(long long)st[4] * (1.0/4096.0));
        float g1 = (float)((double)(long long)st[5] * (1.0/4096.0));
        float g2 = (float)((double)(long long)st[6] * (1.0/4096.0));
        float h  = (float)((double)(long long)st[7] * (1.0/2048.0));
        float cmx = unfx(st[8]), cmy = unfx(st[9]), cmz = unfx(st[10]);
        float valid = cnt > 0.f ? 1.f : 0.f;
        float safe = fmaxf(cnt, 1.f);
        float isafe = 1.f/safe;
        float c0 = (cmc == 1.f) ? cmx : mx*isafe;
        float c1 = (cmc == 1.f) ? cmy : my*isafe;
        float c2 = (cmc == 1.f) ? cmz : mz*isafe;
        float sm0 = g0*isafe, sm1 = g1*isafe, sm2 = g2*isafe;
        float vs = h - 2.f*(sm0*g0 + sm1*g1 + sm2*g2)
                 + (sm0*sm0 + sm1*sm1 + sm2*sm2)*cnt;
        s_vrk[t] = vs*isafe*(1.f/3.f);
        s_val[t] = valid;
        float* dd = &derived[(size_t)t*8];
        dd[0] = expf(10.f*sm0)*L2E; dd[1] = expf(10.f*sm1)*L2E; dd[2] = expf(10.f*sm2)*L2E;
        dd[3] = c0; dd[4] = c1; dd[5] = c2; dd[6] = cnt;
    }
    __syncthreads();
    if (t < 2){
        float obj = 0.f, vp = 0.f;
        #pragma unroll
        for (int kq = 0; kq < 8; kq++){
            obj += s_val[t*8 + kq];
            vp += s_val[t*8 + kq]*s_vrk[t*8 + kq];
        }
        obj = fmaxf(obj, 1.f);
        var_part[t] = vp / obj;
        s_obj[t] = obj;
    }
    __syncthreads();
    if (t < 16) derived[(size_t)t*8 + 7] = s_val[t]/s_obj[t >> 3];
}

// ---------------- single-pass all-k windowed histogram + bg/fg seed ----------------
__global__ __launch_bounds__(512, 4) void k_hist(
        const float* __restrict__ pred,
        const int* __restrict__ inst, const int* __restrict__ lab,
        const float* __restrict__ derived,
        u32* __restrict__ hs, u64* __restrict__ bgsh){
    __shared__ u32 lh[KK*2*NB];   /* 16 KB */
    __shared__ u64 fgfx, bgfx;
    int sx = blockIdx.x, b = blockIdx.y;
    if (threadIdx.x == 0){ fgfx = 0ull; bgfx = 0ull; }
    for (int i = threadIdx.x; i < KK*2*NB; i += 512) lh[i] = 0u;
    float ax[KK], ay[KK], az[KK], cx[KK], cy[KK], cz[KK];
    const float* db = derived + (size_t)b*KK*8;
    #pragma unroll
    for (int k = 0; k < KK; k++){
        ax[k]=rfl(db[k*8+0]); ay[k]=rfl(db[k*8+1]); az[k]=rfl(db[k*8+2]);
        cx[k]=rfl(db[k*8+3]); cy[k]=rfl(db[k*8+4]); cz[k]=rfl(db[k*8+5]);
    }
    __syncthreads();
    const float* pb = pred + (size_t)b*7*NV;
    const int* ib = inst + (size_t)b*NV;
    const int* lb = lab + (size_t)b*NV;
    int g = sx*VPB + threadIdx.x*8;
    const float4* q0 = (const float4*)&pb[g];
    const float4* q1 = (const float4*)&pb[(size_t)NV + g];
    const float4* q2 = (const float4*)&pb[2*(size_t)NV + g];
    const float4* q6 = (const float4*)&pb[6*(size_t)NV + g];
    float4 a0 = q0[0], b0 = q0[1];
    float4 a1 = q1[0], b1 = q1[1];
    float4 a2 = q2[0], b2 = q2[1];
    float4 a6 = q6[0], b6 = q6[1];
    const int4* qi = (const int4*)&ib[g];
    int4 i0 = qi[0], i1 = qi[1];
    const int4* ql = (const int4*)&lb[g];
    int4 l0 = ql[0], l1 = ql[1];
    int iy = g / WW;
    int ix = g - iy*WW;
    int iz = iy / HH; iy -= iz*HH;
    float xm = ix*(1.f/(WW-1)), ym = iy*(1.f/(HH-1)), zm = iz*(1.f/(DD-1));
    float p0a[8] = {a0.x,a0.y,a0.z,a0.w,b0.x,b0.y,b0.z,b0.w};
    float p1a[8] = {a1.x,a1.y,a1.z,a1.w,b1.x,b1.y,b1.z,b1.w};
    float p2a[8] = {a2.x,a2.y,a2.z,a2.w,b2.x,b2.y,b2.z,b2.w};
    float p6a[8] = {a6.x,a6.y,a6.z,a6.w,b6.x,b6.y,b6.z,b6.w};
    int iva[8] = {i0.x,i0.y,i0.z,i0.w,i1.x,i1.y,i1.z,i1.w};
    int lba[8] = {l0.x,l0.y,l0.z,l0.w,l1.x,l1.y,l1.z,l1.w};
    float e0[8], e1[8], e2[8], sd[8];
    float bgacc = 0.f;
    #pragma unroll
    for (int j = 0; j < 8; j++){
        e0[j] = tanh_f(p0a[j]) + xm + j*(1.f/(WW-1));
        e1[j] = tanh_f(p1a[j]) + ym;
        e2[j] = tanh_f(p2a[j]) + zm;
        sd[j] = sigm_f(p6a[j]);
        if (lba[j] == 0) bgacc += sd[j]*sd[j];
    }
    float fgacc = 0.f;
    #pragma unroll
    for (int k = 0; k < KK; k++){
        #pragma unroll
        for (int j = 0; j < 8; j++){
            float d0 = e0[j] - cx[k], d1 = e1[j] - cy[k], dz = e2[j] - cz[k];
            float d2 = ax[k]*d0*d0;
            d2 = fmaf(ay[k]*d1, d1, d2);
            d2 = fmaf(az[k]*dz, dz, d2);
            float dist = exp2_f(-d2);               /* L2E folded into a's */
            if (iva[j] == k + 1){
                float e = fmaf(-2.f, dist, 2.f);
                int bu = (int)(__float_as_uint(e) >> 19) - BOFF;
                bu = bu < 0 ? 0 : (bu > NB-1 ? NB-1 : bu);
                atomicAdd(&lh[k*512 + bu], 1u);
                fgacc += (sd[j] - dist)*(sd[j] - dist);
            } else {
                /* e = 2*dist: bits(2x)>>19 == (bits(x)>>19)+16 for normals */
                int bu = (int)(__float_as_uint(dist) >> 19) - (BOFF - 16);
                bu = bu < 0 ? 0 : (bu > NB-1 ? NB-1 : bu);
                atomicAdd(&lh[k*512 + NB + bu], 1u);
            }
        }
    }
    #pragma unroll
    for (int off = 32; off > 0; off >>= 1){
        fgacc += __shfl_down(fgacc, off);
        bgacc += __shfl_down(bgacc, off);
    }
    if ((threadIdx.x & 63) == 0){
        if (fgacc != 0.f) atomicAdd(&fgfx, fx(fgacc));
        if (bgacc != 0.f) atomicAdd(&bgfx, fx(bgacc));
    }
    __syncthreads();
    if (threadIdx.x == 0){
        if (bgfx) atomicAdd(&bgsh[(size_t)b*8 + (sx&7)], bgfx);
        if (fgfx) atomicAdd(&bgsh[(size_t)(2+b)*8 + (sx&7)], fgfx);
    }
    u32* out = hs + ((size_t)b*NSL + sx)*(KK*NB);
    for (int i = threadIdx.x; i < KK*NB; i += 512){
        int k = i >> 8, bu = i & 255;
        out[i] = (lh[k*512 + bu] << 16) | lh[k*512 + NB + bu];
    }
}

// ---------------- Lovasz scan over summed hists + fused final (16 blocks) ----------------
__global__ __launch_bounds__(1024) void k_lovasz(
        const u32* __restrict__ hs, const float* __restrict__ derived,
        float* __restrict__ lov, const float* __restrict__ var_part,
        const u64* __restrict__ bgsh, u32* __restrict__ counter,
        float* __restrict__ out){
    int bk = blockIdx.x, b = bk >> 3, k = bk & 7;
    int t = threadIdx.x;
    float gts = derived[(size_t)bk*8 + 6];
    float lv = 0.f;
    __shared__ u64 part[4][NB];
    __shared__ u64 wsum[4];
    __shared__ float racc[NB];
    if (gts >= 0.5f){
        int bu = (NB - 1) - (t & 255);    /* descending error order */
        int sg = t >> 8;
        u32 np = 0, nn = 0;
        const u32* base = hs + (size_t)b*NSL*(KK*NB) + k*NB + bu;
        for (int s = sg; s < NSL; s += 4){
            u32 h = base[(size_t)s*(KK*NB)];
            np += h >> 16; nn += h & 0xFFFFu;
        }
        part[sg][t & 255] = ((u64)np << 32) | nn;
        __syncthreads();
        u64 pack = 0ull, inc = 0ull;
        if (t < NB){
            pack = part[0][t] + part[1][t] + part[2][t] + part[3][t];
            int lane = t & 63;
            inc = pack;
            #pragma unroll
            for (int off = 1; off < 64; off <<= 1){
                u64 n = __shfl_up(inc, off);
                if (lane >= off) inc += n;
            }
            if (lane == 63) wsum[t >> 6] = inc;
        }
        __syncthreads();
        if (t < 4){
            u64 x = wsum[t];
            #pragma unroll
            for (int off = 1; off < 4; off <<= 1){
                u64 n = __shfl_up(x, off);
                if (t >= off) x += n;
            }
            wsum[t] = x;
        }
        __syncthreads();
        float acc = 0.f;
        if (t < NB){
            int wid = t >> 6;
            u64 excl = inc - pack + (wid ? wsum[wid - 1] : 0ull);
            u32 np2 = (u32)(pack >> 32), nn2 = (u32)pack;
            if (np2 | nn2){
                int bu2 = (NB - 1) - t;
                float Pe = (float)(u32)(excl >> 32), Qe = (float)(u32)excl;
                float Pi = Pe + (float)np2, Qi = Qe + (float)nn2;
                float je = 1.f - (gts - Pe)/(gts + Qe);
                float ji = 1.f - (gts - Pi)/(gts + Qi);
                u32 bits = ((u32)(bu2 + BOFF) << 19) | (1u << 18);
                if (bits > 0x40000000u) bits = 0x40000000u;
                acc = __uint_as_float(bits) * (ji - je);
            }
            racc[t] = acc;
        }
        __syncthreads();
        for (int off = 128; off > 0; off >>= 1){
            if (t < off) racc[t] += racc[t + off];
            __syncthreads();
        }
        lv = derived[(size_t)bk*8 + 7] * racc[0];
    }
    if (t == 0){
        __hip_atomic_store(&lov[bk], lv, __ATOMIC_RELEASE, __HIP_MEMORY_SCOPE_AGENT);
        u32 ticket = __hip_atomic_fetch_add(counter, 1u, __ATOMIC_ACQ_REL, __HIP_MEMORY_SCOPE_AGENT);
        if (ticket == 15u){
            float tot = 0.f;
            for (int i = 0; i < 16; i++)
                tot += __hip_atomic_load(&lov[i], __ATOMIC_ACQUIRE, __HIP_MEMORY_SCOPE_AGENT);
            for (int b2 = 0; b2 < BN; b2++){
                float bg = 0.f, fg = 0.f;
                for (int sh = 0; sh < 8; sh++){
                    bg += unfx(bgsh[(size_t)b2*8 + sh]);
                    fg += unfx(bgsh[(size_t)(2+b2)*8 + sh]);
                }
                tot += 10.f*var_part[b2] + (bg + fg)*(1.f/(float)NV);
            }
            out[0] = tot * 0.5f;
        }
    }
}

extern "C" void kernel_launch(void* const* d_in, const int* in_sizes, int n_in,
                              void* d_out, int out_size, void* d_ws, size_t ws_size,
                              hipStream_t stream){
    const float* pred = (const float*)d_in[0];
    const int*   inst = (const int*)d_in[2];
    const int*   lab  = (const int*)d_in[3];
    const void*  cim  = d_in[4];

    char* ws = (char*)d_ws;
    size_t off = 0;
    u32* hs = (u32*)(ws + off);        off += (size_t)BN*NSL*KK*NB*4;   /* 4.72 MB */
    size_t small0 = off;
    u64* ssh = (u64*)(ws + off);       off += (size_t)4*BN*KK*SSLOT*8;  /* stat shards */
    u64* bgsh = (u64*)(ws + off);      off += (size_t)4*8*8;            /* bg/fg shards */
    float* derived = (float*)(ws + off); off += (size_t)BN*KK*8*4;
    float* lov = (float*)(ws + off);   off += 16*4;
    float* var_part = (float*)(ws + off); off += 2*4;
    u32* flags = (u32*)(ws + off);     off += 4*4;
    u32* counter = (u32*)(ws + off);   off += 4;

    (void)hipMemsetAsync(ws + small0, 0, off - small0, stream);
    k_detect<<<dim3(256), dim3(256), 0, stream>>>((const u32*)cim, BN*NV/4, flags);
    k_stats<<<dim3(NSL, BN), dim3(512), 0, stream>>>(pred, inst, cim, flags, ssh, bgsh);
    k_derive<<<1, 64, 0, stream>>>(ssh, derived, var_part);
    k_hist<<<dim3(NSL, BN), dim3(512), 0, stream>>>(pred, inst, lab, derived, hs, bgsh);
    k_lovasz<<<16, 1024, 0, stream>>>(hs, derived, lov, var_part, bgsh, counter, (float*)d_out);
}

// Round 13
// 70.660 us; speedup vs baseline: 1.1556x; 1.1047x over previous
//
#include <hip/hip_runtime.h>
#include <stdint.h>

typedef unsigned long long u64;
typedef unsigned int u32;

#define BN 2
#define DD 32
#define HH 192
#define WW 192
#define NV (DD*HH*WW)   /* 1179648 */
#define KK 8
#define NSL 288         /* blocks per batch, 4096 vox each, within one z-slice */
#define VPB 4096
#define NB 256          /* buckets in window */
#define BOFF 1808       /* 0x38800000>>19 : window floor e = 2^-14 */
#define L2E 1.44269504f
#define SSLOT 11
#define NFRONT 16       /* detect blocks */

__device__ __forceinline__ u64 fx(float v){ return (u64)(long long)llrintf(v*4294967296.0f); }
__device__ __forceinline__ float unfx(u64 v){ return (float)((double)(long long)v*(1.0/4294967296.0)); }
__device__ __forceinline__ float rcp_f(float x){ return __builtin_amdgcn_rcpf(x); }
__device__ __forceinline__ float exp2_f(float x){ return __builtin_amdgcn_exp2f(x); }
__device__ __forceinline__ float tanh_f(float x){ return 1.f - 2.f*rcp_f(1.f + exp2_f(x*(2.f*L2E))); }
__device__ __forceinline__ float sigm_f(float x){ return rcp_f(1.f + exp2_f(-x*L2E)); }
__device__ __forceinline__ float rfl(float x){ return __uint_as_float(__builtin_amdgcn_readfirstlane((int)__float_as_uint(x))); }

// unpack cell (b,k) from 4 shards (R12 ssh layout):
// 0 cnt<<32|cm, 1..3 Six/Siy/Siz, 4..6 Ssig*4096 (signed), 7 Ss2*2048, 8..10 cm fx32
struct Cell { float cnt, cmc, mx, my, mz, g0, g1, g2, h, cmx, cmy, cmz; };
__device__ __forceinline__ Cell load_cell(const u64* __restrict__ ssh, int bb, int kq){
    u64 st[SSLOT];
    #pragma unroll
    for (int s = 0; s < SSLOT; s++){
        u64 a = 0ull;
        #pragma unroll
        for (int sh = 0; sh < 4; sh++)
            a += ssh[((size_t)(sh*BN + bb)*KK + kq)*SSLOT + s];
        st[s] = a;
    }
    Cell c;
    c.cnt = (float)(long long)(st[0] >> 32);
    c.cmc = (float)(u32)st[0];
    c.mx = (float)(long long)st[1] * (1.f/(WW-1));
    c.my = (float)(long long)st[2] * (1.f/(HH-1));
    c.mz = (float)(long long)st[3] * (1.f/(DD-1));
    c.g0 = (float)((double)(long long)st[4] * (1.0/4096.0));
    c.g1 = (float)((double)(long long)st[5] * (1.0/4096.0));
    c.g2 = (float)((double)(long long)st[6] * (1.0/4096.0));
    c.h  = (float)((double)(long long)st[7] * (1.0/2048.0));
    c.cmx = unfx(st[8]); c.cmy = unfx(st[9]); c.cmz = unfx(st[10]);
    return c;
}

// ---------------- front: zero accumulators + detect cim layout ----------------
// fpart[bid] = bit0 fF(float)|bit1 fB(bytes)|bit2 fO(odd-1)|bit3 f1(any-1); plain store.
__global__ __launch_bounds__(1024) void k_front(
        const u32* __restrict__ w, u32* __restrict__ fpart,
        u64* __restrict__ zero_base, int nzero_u64, u32* __restrict__ counter){
    int bid = blockIdx.x;
    if (bid == 0){
        for (int i = threadIdx.x; i < nzero_u64; i += 1024) zero_base[i] = 0ull;
        if (threadIdx.x == 0) *counter = 0u;
    }
    __shared__ u32 lfl;
    if (threadIdx.x == 0) lfl = 0u;
    __syncthreads();
    const int chunk = (BN*NV/4)/NFRONT;
    u32 f = 0;
    for (int i = bid*chunk + threadIdx.x; i < (bid+1)*chunk; i += 1024){
        u32 x = w[i];
        if (x == 0x3F800000u) f |= 1u;
        else if (x > 1u) f |= 2u;
        else if (x == 1u){ f |= 8u; if (i & 1) f |= 4u; }
    }
    if (f) atomicOr(&lfl, f);
    __syncthreads();
    if (threadIdx.x == 0) fpart[bid] = lfl;
}

// ---------------- per-instance statistics: 3 packed u64 LDS atomics/voxel ----------------
__global__ __launch_bounds__(512, 8) void k_stats(
        const float* __restrict__ pred,
        const int* __restrict__ inst,
        const void* __restrict__ cim, const u32* __restrict__ fpart,
        u64* __restrict__ ssh){
    int sx = blockIdx.x, b = blockIdx.y;
    __shared__ u64 bins[8][4][25];       /* 32 replicas, stride 25: 6.4 KB */
    __shared__ u64 cmb[8][KK][4];        /* rare cm sums, per-wave: 2 KB */
    __shared__ int smode;
    for (int i = threadIdx.x; i < 8*4*25; i += 512) ((u64*)bins)[i] = 0ull;
    for (int i = threadIdx.x; i < 8*KK*4; i += 512) ((u64*)cmb)[i] = 0ull;
    if (threadIdx.x == 0){
        u32 fl = 0;
        #pragma unroll
        for (int i = 0; i < NFRONT; i++) fl |= fpart[i];
        smode = (fl & 1u) ? 2 : ((fl & 2u) ? 1 : ((fl & 4u) ? 0 : ((fl & 8u) ? 3 : 0)));
    }
    __syncthreads();
    int mode = smode;
    const float* pb = pred + (size_t)b*7*NV;
    const int* ib = inst + (size_t)b*NV;
    int wv = threadIdx.x >> 6, lp = threadIdx.x & 3;
    int g = sx*VPB + threadIdx.x*8;

    const float4* q0p = (const float4*)&pb[3*(size_t)NV + g];
    const float4* q1p = (const float4*)&pb[4*(size_t)NV + g];
    const float4* q2p = (const float4*)&pb[5*(size_t)NV + g];
    float4 sa0 = q0p[0], sb0 = q0p[1];
    float4 sa1 = q1p[0], sb1 = q1p[1];
    float4 sa2 = q2p[0], sb2 = q2p[1];
    const int4* qi = (const int4*)&ib[g];
    int4 i0 = qi[0], i1 = qi[1];
    int iy = g / WW;
    int ix = g - iy*WW;
    int iz = iy / HH; iy -= iz*HH;
    u64 fxm = fx(ix*(1.f/(WW-1)));
    u64 fdx = fx(1.f/(WW-1));
    u64 fym = fx(iy*(1.f/(HH-1)));
    u64 fzm = fx(iz*(1.f/(DD-1)));
    u32 cv8 = 0;
    size_t gi = (size_t)b*NV + g;
    if (mode == 0){
        int4 c0 = ((const int4*)&((const int*)cim)[gi])[0];
        int4 c1 = ((const int4*)&((const int*)cim)[gi])[1];
        cv8 = (c0.x?1u:0u)|(c0.y?2u:0u)|(c0.z?4u:0u)|(c0.w?8u:0u)
            | (c1.x?16u:0u)|(c1.y?32u:0u)|(c1.z?64u:0u)|(c1.w?128u:0u);
    } else if (mode == 1){
        u64 c = *(const u64*)&((const unsigned char*)cim)[gi];
        #pragma unroll
        for (int j = 0; j < 8; j++) if ((c >> (8*j)) & 0xFFull) cv8 |= 1u << j;
    } else if (mode == 2){
        float4 c0 = ((const float4*)&((const float*)cim)[gi])[0];
        float4 c1 = ((const float4*)&((const float*)cim)[gi])[1];
        cv8 = (c0.x!=0.f?1u:0u)|(c0.y!=0.f?2u:0u)|(c0.z!=0.f?4u:0u)|(c0.w!=0.f?8u:0u)
            | (c1.x!=0.f?16u:0u)|(c1.y!=0.f?32u:0u)|(c1.z!=0.f?64u:0u)|(c1.w!=0.f?128u:0u);
    } else {
        const int4* cc = (const int4*)&((const int*)cim)[2*gi];
        int4 c0 = cc[0], c1 = cc[1], c2 = cc[2], c3 = cc[3];
        cv8 = (c0.x?1u:0u)|(c0.z?2u:0u)|(c1.x?4u:0u)|(c1.z?8u:0u)
            | (c2.x?16u:0u)|(c2.z?32u:0u)|(c3.x?64u:0u)|(c3.z?128u:0u);
    }
    float s0a[8] = {sa0.x,sa0.y,sa0.z,sa0.w,sb0.x,sb0.y,sb0.z,sb0.w};
    float s1a[8] = {sa1.x,sa1.y,sa1.z,sa1.w,sb1.x,sb1.y,sb1.z,sb1.w};
    float s2a[8] = {sa2.x,sa2.y,sa2.z,sa2.w,sb2.x,sb2.y,sb2.z,sb2.w};
    int iva[8] = {i0.x,i0.y,i0.z,i0.w,i1.x,i1.y,i1.z,i1.w};
    #pragma unroll
    for (int j = 0; j < 8; j++){
        int iv = iva[j];
        if (iv >= 1 && iv <= KK){
            u64* bn = &bins[wv][lp][(iv-1)*3];
            u32 cv = (cv8 >> j) & 1u;
            u32 q0 = (u32)llrintf((s0a[j] + 16.f)*4096.f);
            u32 q1 = (u32)llrintf((s1a[j] + 16.f)*4096.f);
            u32 q2 = (u32)llrintf((s2a[j] + 16.f)*4096.f);
            float s2t = s0a[j]*s0a[j] + s1a[j]*s1a[j] + s2a[j]*s2a[j];
            u32 r = (u32)llrintf(fminf(s2t, 512.f)*2048.f);
            atomicAdd(&bn[0], (1ull << 44) | ((u64)(u32)(ix + j) << 24) | ((u64)(u32)iy << 4) | cv);
            atomicAdd(&bn[1], ((u64)q0 << 32) | q1);
            atomicAdd(&bn[2], ((u64)q2 << 32) | r);
            if (cv){
                u64* cb = &cmb[wv][iv-1][0];
                atomicAdd(&cb[0], fxm + (u64)j*fdx);
                atomicAdd(&cb[1], fym);
                atomicAdd(&cb[2], fzm);
            }
        }
    }
    __syncthreads();
    int t = threadIdx.x;
    u64* cell0 = &ssh[((size_t)((sx&3)*BN + b))*KK*SSLOT];
    if (t < KK){
        int k = t;
        u64 sA = 0ull, sB = 0ull, sC = 0ull;
        #pragma unroll
        for (int r2 = 0; r2 < 32; r2++){
            const u64* bn = &bins[r2>>2][r2&3][k*3];
            sA += bn[0]; sB += bn[1]; sC += bn[2];
        }
        u64 cnt = sA >> 44;
        if (cnt){
            u64 six = (sA >> 24) & 0xFFFFFull;
            u64 siy = (sA >> 4) & 0xFFFFFull;
            u64 cm  = sA & 0xFull;
            long long bias = (long long)(cnt * 65536ull);   /* 16*4096 */
            long long g0 = (long long)(sB >> 32) - bias;
            long long g1 = (long long)(sB & 0xFFFFFFFFull) - bias;
            long long g2 = (long long)(sC >> 32) - bias;
            u64 h = sC & 0xFFFFFFFFull;
            u64* cell = cell0 + (size_t)k*SSLOT;
            atomicAdd(&cell[0], (cnt << 32) | cm);
            atomicAdd(&cell[1], six);
            atomicAdd(&cell[2], siy);
            atomicAdd(&cell[3], cnt*(u64)iz);
            atomicAdd(&cell[4], (u64)g0);
            atomicAdd(&cell[5], (u64)g1);
            atomicAdd(&cell[6], (u64)g2);
            atomicAdd(&cell[7], h);
        }
    }
    if (t < KK*3){
        int k = t / 3, s = t - k*3;
        u64 acc = 0ull;
        #pragma unroll
        for (int w = 0; w < 8; w++) acc += cmb[w][k][s];
        if (acc) atomicAdd(&cell0[(size_t)k*SSLOT + 8 + s], acc);
    }
}

// ---------------- all-k windowed histogram + bg/fg seed + prologue-derive ----------------
__global__ __launch_bounds__(512, 4) void k_hist(
        const u64* __restrict__ ssh, const float* __restrict__ pred,
        const int* __restrict__ inst, const int* __restrict__ lab,
        u32* __restrict__ hs, u64* __restrict__ bgsh){
    __shared__ u32 lh[KK*2*NB];   /* 16 KB */
    __shared__ u64 fgfx, bgfx;
    __shared__ float dv[KK*6];
    int sx = blockIdx.x, b = blockIdx.y;
    if (threadIdx.x == 0){ fgfx = 0ull; bgfx = 0ull; }
    for (int i = threadIdx.x; i < KK*2*NB; i += 512) lh[i] = 0u;
    if (threadIdx.x < KK){
        int kq = threadIdx.x;
        Cell c = load_cell(ssh, b, kq);
        float safe = fmaxf(c.cnt, 1.f);
        float isafe = 1.f/safe;
        float c0 = (c.cmc == 1.f) ? c.cmx : c.mx*isafe;
        float c1 = (c.cmc == 1.f) ? c.cmy : c.my*isafe;
        float c2 = (c.cmc == 1.f) ? c.cmz : c.mz*isafe;
        dv[kq*6+0] = expf(10.f*c.g0*isafe)*L2E;
        dv[kq*6+1] = expf(10.f*c.g1*isafe)*L2E;
        dv[kq*6+2] = expf(10.f*c.g2*isafe)*L2E;
        dv[kq*6+3] = c0; dv[kq*6+4] = c1; dv[kq*6+5] = c2;
    }
    __syncthreads();
    float ax[KK], ay[KK], az[KK], cx[KK], cy[KK], cz[KK];
    #pragma unroll
    for (int k = 0; k < KK; k++){
        ax[k]=rfl(dv[k*6+0]); ay[k]=rfl(dv[k*6+1]); az[k]=rfl(dv[k*6+2]);
        cx[k]=rfl(dv[k*6+3]); cy[k]=rfl(dv[k*6+4]); cz[k]=rfl(dv[k*6+5]);
    }
    const float* pb = pred + (size_t)b*7*NV;
    const int* ib = inst + (size_t)b*NV;
    const int* lb = lab + (size_t)b*NV;
    int g = sx*VPB + threadIdx.x*8;
    const float4* q0 = (const float4*)&pb[g];
    const float4* q1 = (const float4*)&pb[(size_t)NV + g];
    const float4* q2 = (const float4*)&pb[2*(size_t)NV + g];
    const float4* q6 = (const float4*)&pb[6*(size_t)NV + g];
    float4 a0 = q0[0], b0 = q0[1];
    float4 a1 = q1[0], b1 = q1[1];
    float4 a2 = q2[0], b2 = q2[1];
    float4 a6 = q6[0], b6 = q6[1];
    const int4* qi = (const int4*)&ib[g];
    int4 i0 = qi[0], i1 = qi[1];
    const int4* ql = (const int4*)&lb[g];
    int4 l0 = ql[0], l1 = ql[1];
    int iy = g / WW;
    int ix = g - iy*WW;
    int iz = iy / HH; iy -= iz*HH;
    float xm = ix*(1.f/(WW-1)), ym = iy*(1.f/(HH-1)), zm = iz*(1.f/(DD-1));
    float p0a[8] = {a0.x,a0.y,a0.z,a0.w,b0.x,b0.y,b0.z,b0.w};
    float p1a[8] = {a1.x,a1.y,a1.z,a1.w,b1.x,b1.y,b1.z,b1.w};
    float p2a[8] = {a2.x,a2.y,a2.z,a2.w,b2.x,b2.y,b2.z,b2.w};
    float p6a[8] = {a6.x,a6.y,a6.z,a6.w,b6.x,b6.y,b6.z,b6.w};
    int iva[8] = {i0.x,i0.y,i0.z,i0.w,i1.x,i1.y,i1.z,i1.w};
    int lba[8] = {l0.x,l0.y,l0.z,l0.w,l1.x,l1.y,l1.z,l1.w};
    float e0[8], e1[8], e2[8], sd[8];
    float bgacc = 0.f;
    #pragma unroll
    for (int j = 0; j < 8; j++){
        e0[j] = tanh_f(p0a[j]) + xm + j*(1.f/(WW-1));
        e1[j] = tanh_f(p1a[j]) + ym;
        e2[j] = tanh_f(p2a[j]) + zm;
        sd[j] = sigm_f(p6a[j]);
        if (lba[j] == 0) bgacc += sd[j]*sd[j];
    }
    float fgacc = 0.f;
    #pragma unroll
    for (int k = 0; k < KK; k++){
        #pragma unroll
        for (int j = 0; j < 8; j++){
            float d0 = e0[j] - cx[k], d1 = e1[j] - cy[k], dz = e2[j] - cz[k];
            float d2 = ax[k]*d0*d0;
            d2 = fmaf(ay[k]*d1, d1, d2);
            d2 = fmaf(az[k]*dz, dz, d2);
            float dist = exp2_f(-d2);               /* L2E folded into a's */
            if (iva[j] == k + 1){
                float e = fmaf(-2.f, dist, 2.f);
                int bu = (int)(__float_as_uint(e) >> 19) - BOFF;
                bu = bu < 0 ? 0 : (bu > NB-1 ? NB-1 : bu);
                atomicAdd(&lh[k*512 + bu], 1u);
                fgacc += (sd[j] - dist)*(sd[j] - dist);
            } else {
                /* e = 2*dist: bits(2x)>>19 == (bits(x)>>19)+16 for normals */
                int bu = (int)(__float_as_uint(dist) >> 19) - (BOFF - 16);
                bu = bu < 0 ? 0 : (bu > NB-1 ? NB-1 : bu);
                atomicAdd(&lh[k*512 + NB + bu], 1u);
            }
        }
    }
    #pragma unroll
    for (int off = 32; off > 0; off >>= 1){
        fgacc += __shfl_down(fgacc, off);
        bgacc += __shfl_down(bgacc, off);
    }
    if ((threadIdx.x & 63) == 0){
        if (fgacc != 0.f) atomicAdd(&fgfx, fx(fgacc));
        if (bgacc != 0.f) atomicAdd(&bgfx, fx(bgacc));
    }
    __syncthreads();
    if (threadIdx.x == 0){
        if (bgfx) atomicAdd(&bgsh[(size_t)b*8 + (sx&7)], bgfx);
        if (fgfx) atomicAdd(&bgsh[(size_t)(2+b)*8 + (sx&7)], fgfx);
    }
    u32* out = hs + ((size_t)b*NSL + sx)*(KK*NB);
    for (int i = threadIdx.x; i < KK*NB; i += 512){
        int k = i >> 8, bu = i & 255;
        out[i] = (lh[k*512 + bu] << 16) | lh[k*512 + NB + bu];
    }
}

// ---------------- Lovasz scan + prologue-derive + fused final (16 blocks) ----------------
__global__ __launch_bounds__(1024) void k_lovasz(
        const u32* __restrict__ hs, const u64* __restrict__ ssh,
        float* __restrict__ lov, const u64* __restrict__ bgsh,
        u32* __restrict__ counter, float* __restrict__ out){
    int bk = blockIdx.x, b = bk >> 3, k = bk & 7;
    int t = threadIdx.x;
    __shared__ float s_cnt[16], s_vrk[16], s_val[16];
    if (t < 16){
        Cell c = load_cell(ssh, t >> 3, t & 7);
        float safe = fmaxf(c.cnt, 1.f);
        float isafe = 1.f/safe;
        float sm0 = c.g0*isafe, sm1 = c.g1*isafe, sm2 = c.g2*isafe;
        float vs = c.h - 2.f*(sm0*c.g0 + sm1*c.g1 + sm2*c.g2)
                 + (sm0*sm0 + sm1*sm1 + sm2*sm2)*c.cnt;
        s_vrk[t] = vs*isafe*(1.f/3.f);
        s_val[t] = c.cnt > 0.f ? 1.f : 0.f;
        s_cnt[t] = c.cnt;
    }
    __syncthreads();
    float gts = s_cnt[bk];
    float obj = fmaxf(s_val[b*8+0]+s_val[b*8+1]+s_val[b*8+2]+s_val[b*8+3]
                     +s_val[b*8+4]+s_val[b*8+5]+s_val[b*8+6]+s_val[b*8+7], 1.f);
    float coef = s_val[bk]/obj;
    float lv = 0.f;
    __shared__ u64 part[4][NB];
    __shared__ u64 wsum[4];
    __shared__ float racc[NB];
    if (gts >= 0.5f){
        int bu = (NB - 1) - (t & 255);    /* descending error order */
        int sg = t >> 8;
        u32 np = 0, nn = 0;
        const u32* base = hs + (size_t)b*NSL*(KK*NB) + k*NB + bu;
        for (int s = sg; s < NSL; s += 4){
            u32 h = base[(size_t)s*(KK*NB)];
            np += h >> 16; nn += h & 0xFFFFu;
        }
        part[sg][t & 255] = ((u64)np << 32) | nn;
        __syncthreads();
        u64 pack = 0ull, inc = 0ull;
        if (t < NB){
            pack = part[0][t] + part[1][t] + part[2][t] + part[3][t];
            int lane = t & 63;
            inc = pack;
            #pragma unroll
            for (int off = 1; off < 64; off <<= 1){
                u64 n = __shfl_up(inc, off);
                if (lane >= off) inc += n;
            }
            if (lane == 63) wsum[t >> 6] = inc;
        }
        __syncthreads();
        if (t < 4){
            u64 x = wsum[t];
            #pragma unroll
            for (int off = 1; off < 4; off <<= 1){
                u64 n = __shfl_up(x, off);
                if (t >= off) x += n;
            }
            wsum[t] = x;
        }
        __syncthreads();
        float acc = 0.f;
        if (t < NB){
            int wid = t >> 6;
            u64 excl = inc - pack + (wid ? wsum[wid - 1] : 0ull);
            u32 np2 = (u32)(pack >> 32), nn2 = (u32)pack;
            if (np2 | nn2){
                int bu2 = (NB - 1) - t;
                float Pe = (float)(u32)(excl >> 32), Qe = (float)(u32)excl;
                float Pi = Pe + (float)np2, Qi = Qe + (float)nn2;
                float je = 1.f - (gts - Pe)/(gts + Qe);
                float ji = 1.f - (gts - Pi)/(gts + Qi);
                u32 bits = ((u32)(bu2 + BOFF) << 19) | (1u << 18);
                if (bits > 0x40000000u) bits = 0x40000000u;
                acc = __uint_as_float(bits) * (ji - je);
            }
            racc[t] = acc;
        }
        __syncthreads();
        for (int off = 128; off > 0; off >>= 1){
            if (t < off) racc[t] += racc[t + off];
            __syncthreads();
        }
        lv = coef * racc[0];
    }
    if (t == 0){
        __hip_atomic_store(&lov[bk], lv, __ATOMIC_RELEASE, __HIP_MEMORY_SCOPE_AGENT);
        u32 ticket = __hip_atomic_fetch_add(counter, 1u, __ATOMIC_ACQ_REL, __HIP_MEMORY_SCOPE_AGENT);
        if (ticket == 15u){
            float tot = 0.f;
            for (int i = 0; i < 16; i++)
                tot += __hip_atomic_load(&lov[i], __ATOMIC_ACQUIRE, __HIP_MEMORY_SCOPE_AGENT);
            for (int b2 = 0; b2 < BN; b2++){
                float objb = fmaxf(s_val[b2*8+0]+s_val[b2*8+1]+s_val[b2*8+2]+s_val[b2*8+3]
                                  +s_val[b2*8+4]+s_val[b2*8+5]+s_val[b2*8+6]+s_val[b2*8+7], 1.f);
                float vp = 0.f;
                for (int kq = 0; kq < 8; kq++) vp += s_val[b2*8+kq]*s_vrk[b2*8+kq];
                float bg = 0.f, fg = 0.f;
                for (int sh = 0; sh < 8; sh++){
                    bg += unfx(bgsh[(size_t)b2*8 + sh]);
                    fg += unfx(bgsh[(size_t)(2+b2)*8 + sh]);
                }
                tot += 10.f*vp/objb + (bg + fg)*(1.f/(float)NV);
            }
            out[0] = tot * 0.5f;
        }
    }
}

extern "C" void kernel_launch(void* const* d_in, const int* in_sizes, int n_in,
                              void* d_out, int out_size, void* d_ws, size_t ws_size,
                              hipStream_t stream){
    const float* pred = (const float*)d_in[0];
    const int*   inst = (const int*)d_in[2];
    const int*   lab  = (const int*)d_in[3];
    const void*  cim  = d_in[4];

    char* ws = (char*)d_ws;
    size_t off = 0;
    u32* hs = (u32*)(ws + off);        off += (size_t)BN*NSL*KK*NB*4;   /* 4.72 MB */
    size_t zero0 = off;
    u64* ssh = (u64*)(ws + off);       off += (size_t)4*BN*KK*SSLOT*8;  /* stat shards */
    u64* bgsh = (u64*)(ws + off);      off += (size_t)4*8*8;            /* bg/fg shards */
    size_t zero_u64 = (off - zero0)/8;
    float* lov = (float*)(ws + off);   off += 16*4;
    u32* counter = (u32*)(ws + off);   off += 4;
    u32* fpart = (u32*)(ws + off);     off += NFRONT*4;

    k_front<<<dim3(NFRONT), dim3(1024), 0, stream>>>((const u32*)cim, fpart,
                                                     (u64*)(ws + zero0), (int)zero_u64, counter);
    k_stats<<<dim3(NSL, BN), dim3(512), 0, stream>>>(pred, inst, cim, fpart, ssh);
    k_hist<<<dim3(NSL, BN), dim3(512), 0, stream>>>(ssh, pred, inst, lab, hs, bgsh);
    k_lovasz<<<16, 1024, 0, stream>>>(hs, ssh, lov, bgsh, counter, (float*)d_out);
}